// Round 10
// baseline (243.509 us; speedup 1.0000x reference)
//
#include <hip/hip_runtime.h>

#define DIMN 1024
#define NH   16
#define HD   64
#define BB   4
#define TT   2048
#define MTOK (BB*TT)   /* 8192 */
#define N3   (3*DIMN)  /* 3072 */

typedef unsigned short u16;
typedef u16   u16x4  __attribute__((ext_vector_type(4)));
typedef __bf16 bf16x8 __attribute__((ext_vector_type(8)));
typedef float float4v __attribute__((ext_vector_type(4)));
typedef _Float16 f16;
typedef f16 f16x2 __attribute__((ext_vector_type(2)));
typedef f16 f16x4 __attribute__((ext_vector_type(4)));
typedef f16 f16x8 __attribute__((ext_vector_type(8)));

#if __has_builtin(__builtin_amdgcn_exp2f)
#define EXP2(x) __builtin_amdgcn_exp2f(x)   // raw v_exp_f32, no OCML fix-up
#else
#define EXP2(x) exp2f(x)
#endif

__device__ __forceinline__ u16 f2bf(float f) {
  union { float f; unsigned u; } v; v.f = f;
  unsigned u = v.u;
  return (u16)((u + 0x7FFFu + ((u >> 16) & 1u)) >> 16);
}
__device__ __forceinline__ u16 f2h(float f) {
  union { f16 h; u16 u; } v; v.h = (f16)f; return v.u;
}

__device__ __forceinline__ void gld_lds16(const void* g, void* l) {
  __builtin_amdgcn_global_load_lds(
      (const __attribute__((address_space(1))) void*)g,
      (__attribute__((address_space(3))) void*)l, 16, 0, 0);
}

__device__ __forceinline__ float4v mfma16bf(bf16x8 a, bf16x8 b, float4v c) {
  return __builtin_amdgcn_mfma_f32_16x16x32_bf16(a, b, c, 0, 0, 0);
}
__device__ __forceinline__ float4v mfma32h(f16x8 a, f16x8 b, float4v c) {
  return __builtin_amdgcn_mfma_f32_16x16x32_f16(a, b, c, 0, 0, 0);
}

// ---------------- fused pre-pass: x->bf16, w_qkv->T bf16, w_out->T bf16 ----------------
#define PREP_CVT   (MTOK*DIMN/1024)          /* 8192 blocks */
#define PREP_TQKV  (N3/32 * DIMN/32)         /* 3072 blocks */
#define PREP_TOUT  (DIMN/32 * DIMN/32)       /* 1024 blocks */
__global__ __launch_bounds__(256) void k_prep(
    const float* __restrict__ x, u16* __restrict__ xb,
    const float* __restrict__ w_qkv, u16* __restrict__ wqkvT,
    const float* __restrict__ w_out, u16* __restrict__ woutT)
{
  __shared__ float tile[32][33];
  const int bid = blockIdx.x, tid = threadIdx.x;
  if (bid < PREP_CVT) {
    int i = (bid * 256 + tid) * 4;
    float4v v = *(const float4v*)(x + i);
    u16x4 o;
    o[0] = f2bf(v[0]); o[1] = f2bf(v[1]); o[2] = f2bf(v[2]); o[3] = f2bf(v[3]);
    *(u16x4*)(xb + i) = o;
    return;
  }
  const float* w; u16* wT; int N, t;
  if (bid < PREP_CVT + PREP_TQKV) { t = bid - PREP_CVT; w = w_qkv; wT = wqkvT; N = N3; }
  else { t = bid - PREP_CVT - PREP_TQKV; w = w_out; wT = woutT; N = DIMN; }
  const int K = DIMN;
  int n0 = (t % (N/32)) * 32, k0 = (t / (N/32)) * 32;
  int tx = tid & 31, ty = tid >> 5;
#pragma unroll
  for (int i = 0; i < 4; ++i)
    tile[ty + i*8][tx] = w[(k0 + ty + i*8)*N + n0 + tx];
  __syncthreads();
#pragma unroll
  for (int i = 0; i < 4; ++i)
    wT[(n0 + ty + i*8)*K + k0 + tx] = f2bf(tile[tx][ty + i*8]);
}

// ---------------- QKV GEMM: xb[8192,1024] @ wqkvT -> scatter Q,K,V (f16) ----------------
// R2/R7-exact BK=32 2-phase structure: the measured optimum for this kernel (69.1 us).
// Five structural variants (256^2 8-phase x2, 4-phase reuse, slab swizzle, BK=64+swz)
// all regressed -- this kernel's performance is carried by 8-blocks/CU occupancy
// overlap (Occ 27%), which every LDS/barrier "improvement" traded away at a net loss.
__global__ __launch_bounds__(256) void k_gemm_qkv(
    const u16* __restrict__ xb, const u16* __restrict__ wT,
    u16* __restrict__ qb, u16* __restrict__ kb, u16* __restrict__ vb2)
{
  __shared__ __align__(16) u16 As[128*32];
  __shared__ __align__(16) u16 Bs[128*32];
  const int m0 = blockIdx.x * 128, n0 = blockIdx.y * 128;
  const int tid = threadIdx.x;
  const int lane = tid & 63, wv = tid >> 6;
  const int quad = lane >> 4, l16 = lane & 15;
  const int wm = (wv >> 1) * 64, wn = (wv & 1) * 64;
  const int c0 = tid, c1 = tid + 256;
  const u16* ga0 = xb + (m0 + (c0 >> 2)) * DIMN + (c0 & 3) * 8;
  const u16* ga1 = xb + (m0 + (c1 >> 2)) * DIMN + (c1 & 3) * 8;
  const u16* gb0 = wT + (n0 + (c0 >> 2)) * DIMN + (c0 & 3) * 8;
  const u16* gb1 = wT + (n0 + (c1 >> 2)) * DIMN + (c1 & 3) * 8;
  char* la0 = (char*)As + c0 * 16; char* la1 = (char*)As + c1 * 16;
  char* lb0 = (char*)Bs + c0 * 16; char* lb1 = (char*)Bs + c1 * 16;

  float4v acc[4][4] = {};

  for (int kt = 0; kt < DIMN; kt += 32) {
    gld_lds16(ga0 + kt, la0);
    gld_lds16(ga1 + kt, la1);
    gld_lds16(gb0 + kt, lb0);
    gld_lds16(gb1 + kt, lb1);
    __syncthreads();
    bf16x8 af[4], bfv[4];
#pragma unroll
    for (int mt = 0; mt < 4; ++mt)
      af[mt] = *(const bf16x8*)&As[(wm + mt*16 + l16)*32 + quad*8];
#pragma unroll
    for (int nt = 0; nt < 4; ++nt)
      bfv[nt] = *(const bf16x8*)&Bs[(wn + nt*16 + l16)*32 + quad*8];
#pragma unroll
    for (int mt = 0; mt < 4; ++mt)
#pragma unroll
      for (int nt = 0; nt < 4; ++nt)
        acc[mt][nt] = mfma16bf(af[mt], bfv[nt], acc[mt][nt]);
    __syncthreads();
  }

  const float QSCALE = 0.125f * 1.4426950408889634f;  // D^-0.5 * log2(e)
#pragma unroll
  for (int mt = 0; mt < 4; ++mt)
#pragma unroll
    for (int nt = 0; nt < 4; ++nt) {
      int col = n0 + wn + nt*16 + l16;
      int which = col >> 10, cc = col & 1023, h = cc >> 6, d = cc & 63;
      int row0 = m0 + wm + mt*16 + quad*4;
      int b = row0 >> 11, t0 = row0 & (TT-1);
      int bh = b*NH + h;
      if (which == 2) {
        // V^T [B,H,D,T]: pack 4 consecutive t at fixed d -> one 8-B store
        u16x4 pk;
#pragma unroll
        for (int r = 0; r < 4; ++r) pk[r] = f2h(acc[mt][nt][r]);
        *(u16x4*)(vb2 + (bh*HD + d)*TT + t0) = pk;
      } else {
        u16* dst = (which == 0) ? qb : kb;
        float s = (which == 0) ? QSCALE : 1.0f;
#pragma unroll
        for (int r = 0; r < 4; ++r)
          dst[(bh*TT + t0 + r)*HD + d] = f2h(acc[mt][nt][r] * s);
      }
    }
}

// ---- flash attention: far-paired q-groups, no online max, unroll-2, raw exp2 ----
// XCD-aware remap: 1-D grid of 1024; xcd = id&7. Each XCD owns 8 heads ->
// per-XCD K/V working set ~4 MB ~= one L2 (verified: FETCH 125->37 MB).
// PV + denom use the K=32 f16 MFMA shape.
__global__ __launch_bounds__(256) void k_attn(
    const u16* __restrict__ qb, const u16* __restrict__ kb,
    const u16* __restrict__ vb2, u16* __restrict__ ab)
{
  __shared__ __align__(16) u16 Ks0[64*64];
  __shared__ __align__(16) u16 Ks1[64*64];
  __shared__ __align__(16) u16 Vt0[64*64];
  __shared__ __align__(16) u16 Vt1[64*64];
  const int id = (int)blockIdx.x;
  const int xcd = id & 7, slot = id >> 3;
  const int bh = xcd * 8 + (slot & 7);     // 8 heads per XCD
  const int jA = slot >> 3;                // pair index 0..15
  const int b = bh >> 4, h = bh & 15;
  const int qg0 = jA * 64;                 // light group (jA+1 tiles)
  const int qg1 = (31 - jA) * 64;          // heavy group (32-jA tiles)
  const int tid = threadIdx.x, lane = tid & 63, wv = tid >> 6;
  const int quad = lane >> 4, l16 = lane & 15;
  const u16* Qb = qb + bh * (TT*HD);
  const u16* Kb = kb + bh * (TT*HD);
  const u16* Vb = vb2 + bh * (HD*TT);

  // Q fragments (B operand of S^T MFMA): q = qg[g] + wv*16 + l16
  f16x8 bq[2][2];
  {
    int qr0 = qg0 + wv*16 + l16;
    bq[0][0] = *(const f16x8*)(Qb + qr0*HD + quad*8);
    bq[0][1] = *(const f16x8*)(Qb + qr0*HD + 32 + quad*8);
    int qr1 = qg1 + wv*16 + l16;
    bq[1][0] = *(const f16x8*)(Qb + qr1*HD + quad*8);
    bq[1][1] = *(const f16x8*)(Qb + qr1*HD + 32 + quad*8);
  }

  float4v o[2][4] = {};    // O: rows q=quad*4+r, cols d=dt*16+l16
  float4v ol[2] = {};      // row-sum (softmax denom) accumulator, row layout

  // hoisted fragment byte-offsets (loop-invariant; LDS base folds to imm)
  int kof0[4], kof1[4], vof[4][4];
#pragma unroll
  for (int st = 0; st < 4; ++st) {
    int srow = st*16 + l16, sw = srow & 7;
    kof0[st] = srow*128 + ((quad ^ sw) * 16);
    kof1[st] = srow*128 + (((4 + quad) ^ sw) * 16);
#pragma unroll
    for (int dt = 0; dt < 4; ++dt) {
      int vrow = dt*16 + l16, vsw = vrow & 7;
      int chunk = st*2 + (quad >> 1);
      vof[st][dt] = vrow*128 + ((chunk ^ vsw) * 16) + (quad & 1) * 8;
    }
  }

  const int cA = tid, cB = tid + 256;
  const int rowA = cA >> 3, posA = cA & 7, rowB = cB >> 3, posB = cB & 7;
  const int gA = posA ^ (rowA & 7), gB = posB ^ (rowB & 7);

  const int nt = (qg1 >> 6) + 1;               // s-tiles: 0..qg1 inclusive
  const f16x8 ones8 = {(f16)1.f, (f16)1.f, (f16)1.f, (f16)1.f,
                       (f16)1.f, (f16)1.f, (f16)1.f, (f16)1.f};
  const int ql = wv*16 + l16;     // local q within a 64-q group

#define PREFETCH(s1, Kd, Vd) do {                                   \
    gld_lds16(Kb + ((s1)+rowA)*HD + gA*8, (char*)(Kd) + cA*16);     \
    gld_lds16(Kb + ((s1)+rowB)*HD + gB*8, (char*)(Kd) + cB*16);     \
    gld_lds16(Vb + rowA*TT + (s1) + gA*8, (char*)(Vd) + cA*16);     \
    gld_lds16(Vb + rowB*TT + (s1) + gB*8, (char*)(Vd) + cB*16);     \
  } while (0)

#define TILE_BODY(K_, V_, i) do {                                           \
    const bool g0a = ((i) <= jA);                                           \
    float4v sc[2][4];                                                       \
    __builtin_amdgcn_s_setprio(1);                                          \
    _Pragma("unroll")                                                       \
    for (int st = 0; st < 4; ++st) {                                        \
      f16x8 ak0 = *(const f16x8*)((const char*)(K_) + kof0[st]);            \
      f16x8 ak1 = *(const f16x8*)((const char*)(K_) + kof1[st]);            \
      if (g0a) {                                                            \
        float4v s = {};                                                     \
        s = mfma32h(ak0, bq[0][0], s);                                      \
        s = mfma32h(ak1, bq[0][1], s);                                      \
        sc[0][st] = s;                                                      \
      }                                                                     \
      float4v s = {};                                                       \
      s = mfma32h(ak0, bq[1][0], s);                                        \
      s = mfma32h(ak1, bq[1][1], s);                                        \
      sc[1][st] = s;                                                        \
    }                                                                       \
    __builtin_amdgcn_s_setprio(0);                                          \
    if ((i) == jA) {                                                        \
      _Pragma("unroll")                                                     \
      for (int st = 0; st < 4; ++st)                                        \
        _Pragma("unroll")                                                   \
        for (int r = 0; r < 4; ++r)                                         \
          if (st*16 + quad*4 + r > ql) sc[0][st][r] = -1e30f;               \
    }                                                                       \
    if ((i) == nt - 1) {                                                    \
      _Pragma("unroll")                                                     \
      for (int st = 0; st < 4; ++st)                                        \
        _Pragma("unroll")                                                   \
        for (int r = 0; r < 4; ++r)                                         \
          if (st*16 + quad*4 + r > ql) sc[1][st][r] = -1e30f;               \
    }                                                                       \
    f16x8 ap8[2][2];                                                        \
    _Pragma("unroll")                                                       \
    for (int g = 0; g < 2; ++g) {                                           \
      if (g == 0 && !g0a) continue;                                         \
      _Pragma("unroll")                                                     \
      for (int sp = 0; sp < 2; ++sp) {                                      \
        float p0 = EXP2(sc[g][2*sp][0]);                                    \
        float p1 = EXP2(sc[g][2*sp][1]);                                    \
        float p2 = EXP2(sc[g][2*sp][2]);                                    \
        float p3 = EXP2(sc[g][2*sp][3]);                                    \
        float p4 = EXP2(sc[g][2*sp+1][0]);                                  \
        float p5 = EXP2(sc[g][2*sp+1][1]);                                  \
        float p6 = EXP2(sc[g][2*sp+1][2]);                                  \
        float p7 = EXP2(sc[g][2*sp+1][3]);                                  \
        f16x2 a01 = __builtin_bit_cast(f16x2, __builtin_amdgcn_cvt_pkrtz(p0, p1)); \
        f16x2 a23 = __builtin_bit_cast(f16x2, __builtin_amdgcn_cvt_pkrtz(p2, p3)); \
        f16x2 a45 = __builtin_bit_cast(f16x2, __builtin_amdgcn_cvt_pkrtz(p4, p5)); \
        f16x2 a67 = __builtin_bit_cast(f16x2, __builtin_amdgcn_cvt_pkrtz(p6, p7)); \
        f16x4 alo = __builtin_shufflevector(a01, a23, 0, 1, 2, 3);          \
        f16x4 ahi = __builtin_shufflevector(a45, a67, 0, 1, 2, 3);          \
        ap8[g][sp] = __builtin_shufflevector(alo, ahi, 0,1,2,3,4,5,6,7);    \
      }                                                                     \
      ol[g] = mfma32h(ap8[g][0], ones8, ol[g]);                             \
      ol[g] = mfma32h(ap8[g][1], ones8, ol[g]);                             \
    }                                                                       \
    __builtin_amdgcn_s_setprio(1);                                          \
    _Pragma("unroll")                                                       \
    for (int sp = 0; sp < 2; ++sp)                                          \
      _Pragma("unroll")                                                     \
      for (int dt = 0; dt < 4; ++dt) {                                      \
        f16x4 bl = *(const f16x4*)((const char*)(V_) + vof[2*sp][dt]);      \
        f16x4 bh2 = *(const f16x4*)((const char*)(V_) + vof[2*sp+1][dt]);   \
        f16x8 bv8 = __builtin_shufflevector(bl, bh2, 0,1,2,3,4,5,6,7);      \
        if (g0a) o[0][dt] = mfma32h(ap8[0][sp], bv8, o[0][dt]);             \
        o[1][dt] = mfma32h(ap8[1][sp], bv8, o[1][dt]);                      \
      }                                                                     \
    __builtin_amdgcn_s_setprio(0);                                          \
  } while (0)

  // prologue: tile 0 -> buf 0
  PREFETCH(0, Ks0, Vt0);

  for (int ii = 0; ii < nt; ii += 2) {
    __syncthreads();                       // buf0 (tile ii) resident
    if (ii + 1 < nt) PREFETCH((ii+1)*64, Ks1, Vt1);
    TILE_BODY(Ks0, Vt0, ii);
    if (ii + 1 < nt) {
      __syncthreads();                     // buf1 (tile ii+1) resident
      if (ii + 2 < nt) PREFETCH((ii+2)*64, Ks0, Vt0);
      TILE_BODY(Ks1, Vt1, ii+1);
    }
  }
#undef TILE_BODY
#undef PREFETCH

  // epilogue: normalize; denom already in row layout
#pragma unroll
  for (int g = 0; g < 2; ++g) {
    int qg = g ? qg1 : qg0;
#pragma unroll
    for (int r = 0; r < 4; ++r) {
      float inv_r = 1.0f / ol[g][r];
      int t = qg + wv*16 + quad*4 + r;
#pragma unroll
      for (int dt = 0; dt < 4; ++dt)
        ab[(b*TT + t)*DIMN + h*HD + dt*16 + l16] = f2bf(o[g][dt][r] * inv_r);
    }
  }
}

// ---------------- output GEMM: 128x128, BK=64, 2-phase, swizzled LDS ----------------
// R9 variant kept: grid is only 512 blocks -> 2 blocks/CU grid-limited, so the
// 32 KB LDS costs no occupancy here (unlike qkv) and the halved barrier count +
// zero bank conflicts are pure win (~3.5 us inferred from R9 totals).
__global__ __launch_bounds__(256) void k_gemm_out(
    const u16* __restrict__ ab, const u16* __restrict__ wT, float* __restrict__ out)
{
  __shared__ __align__(16) u16 As[128*64];
  __shared__ __align__(16) u16 Bs[128*64];
  const int m0 = blockIdx.x * 128, n0 = blockIdx.y * 128;
  const int tid = threadIdx.x;
  const int lane = tid & 63, wv = tid >> 6;
  const int quad = lane >> 4, l16 = lane & 15;
  const int wm = (wv >> 1) * 64, wn = (wv & 1) * 64;

  const char* gA[4]; const char* gB[4]; int lofs[4];
#pragma unroll
  for (int l = 0; l < 4; ++l) {
    int c = l*256 + tid;
    int row = c >> 3, pos = c & 7;
    int ps = pos ^ (row & 7);
    gA[l] = (const char*)ab + (size_t)(m0 + row)*2048 + (size_t)(ps*16);
    gB[l] = (const char*)wT + (size_t)(n0 + row)*2048 + (size_t)(ps*16);
    lofs[l] = c*16;
  }

  int aOff[4][2], bOff[4][2];
#pragma unroll
  for (int kh = 0; kh < 2; ++kh) {
    int px = ((kh*4 + quad) ^ (l16 & 7)) * 16;
#pragma unroll
    for (int mt = 0; mt < 4; ++mt) {
      aOff[mt][kh] = (wm + mt*16 + l16)*128 + px;
      bOff[mt][kh] = (wn + mt*16 + l16)*128 + px;
    }
  }

  float4v acc[4][4] = {};

  for (int kt = 0; kt < DIMN; kt += 64) {
#pragma unroll
    for (int l = 0; l < 4; ++l) gld_lds16(gA[l] + kt*2, (char*)As + lofs[l]);
#pragma unroll
    for (int l = 0; l < 4; ++l) gld_lds16(gB[l] + kt*2, (char*)Bs + lofs[l]);
    __syncthreads();
    bf16x8 af[4][2], bfv[4][2];
#pragma unroll
    for (int mt = 0; mt < 4; ++mt) {
      af[mt][0]  = *(const bf16x8*)((const char*)As + aOff[mt][0]);
      af[mt][1]  = *(const bf16x8*)((const char*)As + aOff[mt][1]);
      bfv[mt][0] = *(const bf16x8*)((const char*)Bs + bOff[mt][0]);
      bfv[mt][1] = *(const bf16x8*)((const char*)Bs + bOff[mt][1]);
    }
#pragma unroll
    for (int mt = 0; mt < 4; ++mt)
#pragma unroll
      for (int nt = 0; nt < 4; ++nt) {
        acc[mt][nt] = mfma16bf(af[mt][0], bfv[nt][0], acc[mt][nt]);
        acc[mt][nt] = mfma16bf(af[mt][1], bfv[nt][1], acc[mt][nt]);
      }
    __syncthreads();
  }
#pragma unroll
  for (int mt = 0; mt < 4; ++mt)
#pragma unroll
    for (int nt = 0; nt < 4; ++nt) {
      int col = n0 + wn + nt*16 + l16;
#pragma unroll
      for (int r = 0; r < 4; ++r) {
        int row = m0 + wm + mt*16 + quad*4 + r;
        out[row*DIMN + col] = acc[mt][nt][r];
      }
    }
}

extern "C" void kernel_launch(void* const* d_in, const int* in_sizes, int n_in,
                              void* d_out, int out_size, void* d_ws, size_t ws_size,
                              hipStream_t stream) {
  const float* x     = (const float*)d_in[0];
  const float* w_qkv = (const float*)d_in[1];
  const float* w_out = (const float*)d_in[2];
  float* out = (float*)d_out;
  char* ws = (char*)d_ws;
  u16* xb    = (u16*)(ws);
  u16* wqkvT = (u16*)(ws + (16u << 20));
  u16* woutT = (u16*)(ws + (22u << 20));
  u16* qbuf  = (u16*)(ws + (24u << 20));
  u16* kbuf  = (u16*)(ws + (40u << 20));
  u16* vbuf  = (u16*)(ws + (56u << 20));
  u16* abuf  = xb;  // x dead after QKV GEMM; reuse for attention output

  k_prep<<<dim3(PREP_CVT + PREP_TQKV + PREP_TOUT), 256, 0, stream>>>(
      x, xb, w_qkv, wqkvT, w_out, woutT);
  k_gemm_qkv<<<dim3(MTOK/128, N3/128), 256, 0, stream>>>(xb, wqkvT, qbuf, kbuf, vbuf);
  k_attn<<<dim3(16 * BB * NH), 256, 0, stream>>>(qbuf, kbuf, vbuf, abuf);
  k_gemm_out<<<dim3(MTOK/128, DIMN/128), 256, 0, stream>>>(abuf, woutT, out);
}

// Round 11
// 237.975 us; speedup vs baseline: 1.0233x; 1.0233x over previous
//
#include <hip/hip_runtime.h>

#define DIMN 1024
#define NH   16
#define HD   64
#define BB   4
#define TT   2048
#define MTOK (BB*TT)   /* 8192 */
#define N3   (3*DIMN)  /* 3072 */

typedef unsigned short u16;
typedef u16   u16x4  __attribute__((ext_vector_type(4)));
typedef __bf16 bf16x8 __attribute__((ext_vector_type(8)));
typedef float float4v __attribute__((ext_vector_type(4)));
typedef _Float16 f16;
typedef f16 f16x2 __attribute__((ext_vector_type(2)));
typedef f16 f16x4 __attribute__((ext_vector_type(4)));
typedef f16 f16x8 __attribute__((ext_vector_type(8)));

#if __has_builtin(__builtin_amdgcn_exp2f)
#define EXP2(x) __builtin_amdgcn_exp2f(x)   // raw v_exp_f32, no OCML fix-up
#else
#define EXP2(x) exp2f(x)
#endif

__device__ __forceinline__ u16 f2bf(float f) {
  union { float f; unsigned u; } v; v.f = f;
  unsigned u = v.u;
  return (u16)((u + 0x7FFFu + ((u >> 16) & 1u)) >> 16);
}
__device__ __forceinline__ u16 f2h(float f) {
  union { f16 h; u16 u; } v; v.h = (f16)f; return v.u;
}

__device__ __forceinline__ void gld_lds16(const void* g, void* l) {
  __builtin_amdgcn_global_load_lds(
      (const __attribute__((address_space(1))) void*)g,
      (__attribute__((address_space(3))) void*)l, 16, 0, 0);
}

__device__ __forceinline__ float4v mfma16bf(bf16x8 a, bf16x8 b, float4v c) {
  return __builtin_amdgcn_mfma_f32_16x16x32_bf16(a, b, c, 0, 0, 0);
}
__device__ __forceinline__ float4v mfma32h(f16x8 a, f16x8 b, float4v c) {
  return __builtin_amdgcn_mfma_f32_16x16x32_f16(a, b, c, 0, 0, 0);
}

// ---------------- fused pre-pass: x->bf16, w_qkv->T bf16, w_out->T bf16 ----------------
#define PREP_CVT   (MTOK*DIMN/1024)          /* 8192 blocks */
#define PREP_TQKV  (N3/32 * DIMN/32)         /* 3072 blocks */
#define PREP_TOUT  (DIMN/32 * DIMN/32)       /* 1024 blocks */
__global__ __launch_bounds__(256) void k_prep(
    const float* __restrict__ x, u16* __restrict__ xb,
    const float* __restrict__ w_qkv, u16* __restrict__ wqkvT,
    const float* __restrict__ w_out, u16* __restrict__ woutT)
{
  __shared__ float tile[32][33];
  const int bid = blockIdx.x, tid = threadIdx.x;
  if (bid < PREP_CVT) {
    int i = (bid * 256 + tid) * 4;
    float4v v = *(const float4v*)(x + i);
    u16x4 o;
    o[0] = f2bf(v[0]); o[1] = f2bf(v[1]); o[2] = f2bf(v[2]); o[3] = f2bf(v[3]);
    *(u16x4*)(xb + i) = o;
    return;
  }
  const float* w; u16* wT; int N, t;
  if (bid < PREP_CVT + PREP_TQKV) { t = bid - PREP_CVT; w = w_qkv; wT = wqkvT; N = N3; }
  else { t = bid - PREP_CVT - PREP_TQKV; w = w_out; wT = woutT; N = DIMN; }
  const int K = DIMN;
  int n0 = (t % (N/32)) * 32, k0 = (t / (N/32)) * 32;
  int tx = tid & 31, ty = tid >> 5;
#pragma unroll
  for (int i = 0; i < 4; ++i)
    tile[ty + i*8][tx] = w[(k0 + ty + i*8)*N + n0 + tx];
  __syncthreads();
#pragma unroll
  for (int i = 0; i < 4; ++i)
    wT[(n0 + ty + i*8)*K + k0 + tx] = f2bf(tile[tx][ty + i*8]);
}

// ---------------- QKV GEMM: xb[8192,1024] @ wqkvT -> scatter Q,K,V (f16) ----------------
// R2/R7-exact BK=32 2-phase structure: the measured optimum for this kernel (69.1 us).
// Five structural variants (256^2 8-phase x2, 4-phase reuse, slab swizzle, BK=64+swz)
// all regressed -- this kernel's performance is carried by 8-blocks/CU occupancy
// overlap (Occ 27%), which every LDS/barrier "improvement" traded away at a net loss.
__global__ __launch_bounds__(256) void k_gemm_qkv(
    const u16* __restrict__ xb, const u16* __restrict__ wT,
    u16* __restrict__ qb, u16* __restrict__ kb, u16* __restrict__ vb2)
{
  __shared__ __align__(16) u16 As[128*32];
  __shared__ __align__(16) u16 Bs[128*32];
  const int m0 = blockIdx.x * 128, n0 = blockIdx.y * 128;
  const int tid = threadIdx.x;
  const int lane = tid & 63, wv = tid >> 6;
  const int quad = lane >> 4, l16 = lane & 15;
  const int wm = (wv >> 1) * 64, wn = (wv & 1) * 64;
  const int c0 = tid, c1 = tid + 256;
  const u16* ga0 = xb + (m0 + (c0 >> 2)) * DIMN + (c0 & 3) * 8;
  const u16* ga1 = xb + (m0 + (c1 >> 2)) * DIMN + (c1 & 3) * 8;
  const u16* gb0 = wT + (n0 + (c0 >> 2)) * DIMN + (c0 & 3) * 8;
  const u16* gb1 = wT + (n0 + (c1 >> 2)) * DIMN + (c1 & 3) * 8;
  char* la0 = (char*)As + c0 * 16; char* la1 = (char*)As + c1 * 16;
  char* lb0 = (char*)Bs + c0 * 16; char* lb1 = (char*)Bs + c1 * 16;

  float4v acc[4][4] = {};

  for (int kt = 0; kt < DIMN; kt += 32) {
    gld_lds16(ga0 + kt, la0);
    gld_lds16(ga1 + kt, la1);
    gld_lds16(gb0 + kt, lb0);
    gld_lds16(gb1 + kt, lb1);
    __syncthreads();
    bf16x8 af[4], bfv[4];
#pragma unroll
    for (int mt = 0; mt < 4; ++mt)
      af[mt] = *(const bf16x8*)&As[(wm + mt*16 + l16)*32 + quad*8];
#pragma unroll
    for (int nt = 0; nt < 4; ++nt)
      bfv[nt] = *(const bf16x8*)&Bs[(wn + nt*16 + l16)*32 + quad*8];
#pragma unroll
    for (int mt = 0; mt < 4; ++mt)
#pragma unroll
      for (int nt = 0; nt < 4; ++nt)
        acc[mt][nt] = mfma16bf(af[mt], bfv[nt], acc[mt][nt]);
    __syncthreads();
  }

  const float QSCALE = 0.125f * 1.4426950408889634f;  // D^-0.5 * log2(e)
#pragma unroll
  for (int mt = 0; mt < 4; ++mt)
#pragma unroll
    for (int nt = 0; nt < 4; ++nt) {
      int col = n0 + wn + nt*16 + l16;
      int which = col >> 10, cc = col & 1023, h = cc >> 6, d = cc & 63;
      int row0 = m0 + wm + mt*16 + quad*4;
      int b = row0 >> 11, t0 = row0 & (TT-1);
      int bh = b*NH + h;
      if (which == 2) {
        // V^T [B,H,D,T]: pack 4 consecutive t at fixed d -> one 8-B store
        u16x4 pk;
#pragma unroll
        for (int r = 0; r < 4; ++r) pk[r] = f2h(acc[mt][nt][r]);
        *(u16x4*)(vb2 + (bh*HD + d)*TT + t0) = pk;
      } else {
        u16* dst = (which == 0) ? qb : kb;
        float s = (which == 0) ? QSCALE : 1.0f;
#pragma unroll
        for (int r = 0; r < 4; ++r)
          dst[(bh*TT + t0 + r)*HD + d] = f2h(acc[mt][nt][r] * s);
      }
    }
}

// ---- flash attention: far-paired q-groups, no online max, unroll-2, raw exp2 ----
// XCD-aware remap: 1-D grid of 1024; xcd = id&7. Each XCD owns 8 heads ->
// per-XCD K/V working set ~4 MB ~= one L2 (verified: FETCH 125->37 MB).
// PV + denom use the K=32 f16 MFMA shape.
__global__ __launch_bounds__(256) void k_attn(
    const u16* __restrict__ qb, const u16* __restrict__ kb,
    const u16* __restrict__ vb2, u16* __restrict__ ab)
{
  __shared__ __align__(16) u16 Ks0[64*64];
  __shared__ __align__(16) u16 Ks1[64*64];
  __shared__ __align__(16) u16 Vt0[64*64];
  __shared__ __align__(16) u16 Vt1[64*64];
  const int id = (int)blockIdx.x;
  const int xcd = id & 7, slot = id >> 3;
  const int bh = xcd * 8 + (slot & 7);     // 8 heads per XCD
  const int jA = slot >> 3;                // pair index 0..15
  const int b = bh >> 4, h = bh & 15;
  const int qg0 = jA * 64;                 // light group (jA+1 tiles)
  const int qg1 = (31 - jA) * 64;          // heavy group (32-jA tiles)
  const int tid = threadIdx.x, lane = tid & 63, wv = tid >> 6;
  const int quad = lane >> 4, l16 = lane & 15;
  const u16* Qb = qb + bh * (TT*HD);
  const u16* Kb = kb + bh * (TT*HD);
  const u16* Vb = vb2 + bh * (HD*TT);

  // Q fragments (B operand of S^T MFMA): q = qg[g] + wv*16 + l16
  f16x8 bq[2][2];
  {
    int qr0 = qg0 + wv*16 + l16;
    bq[0][0] = *(const f16x8*)(Qb + qr0*HD + quad*8);
    bq[0][1] = *(const f16x8*)(Qb + qr0*HD + 32 + quad*8);
    int qr1 = qg1 + wv*16 + l16;
    bq[1][0] = *(const f16x8*)(Qb + qr1*HD + quad*8);
    bq[1][1] = *(const f16x8*)(Qb + qr1*HD + 32 + quad*8);
  }

  float4v o[2][4] = {};    // O: rows q=quad*4+r, cols d=dt*16+l16
  float4v ol[2] = {};      // row-sum (softmax denom) accumulator, row layout

  // hoisted fragment byte-offsets (loop-invariant; LDS base folds to imm)
  int kof0[4], kof1[4], vof[4][4];
#pragma unroll
  for (int st = 0; st < 4; ++st) {
    int srow = st*16 + l16, sw = srow & 7;
    kof0[st] = srow*128 + ((quad ^ sw) * 16);
    kof1[st] = srow*128 + (((4 + quad) ^ sw) * 16);
#pragma unroll
    for (int dt = 0; dt < 4; ++dt) {
      int vrow = dt*16 + l16, vsw = vrow & 7;
      int chunk = st*2 + (quad >> 1);
      vof[st][dt] = vrow*128 + ((chunk ^ vsw) * 16) + (quad & 1) * 8;
    }
  }

  const int cA = tid, cB = tid + 256;
  const int rowA = cA >> 3, posA = cA & 7, rowB = cB >> 3, posB = cB & 7;
  const int gA = posA ^ (rowA & 7), gB = posB ^ (rowB & 7);

  const int nt = (qg1 >> 6) + 1;               // s-tiles: 0..qg1 inclusive
  const f16x8 ones8 = {(f16)1.f, (f16)1.f, (f16)1.f, (f16)1.f,
                       (f16)1.f, (f16)1.f, (f16)1.f, (f16)1.f};
  const int ql = wv*16 + l16;     // local q within a 64-q group

#define PREFETCH(s1, Kd, Vd) do {                                   \
    gld_lds16(Kb + ((s1)+rowA)*HD + gA*8, (char*)(Kd) + cA*16);     \
    gld_lds16(Kb + ((s1)+rowB)*HD + gB*8, (char*)(Kd) + cB*16);     \
    gld_lds16(Vb + rowA*TT + (s1) + gA*8, (char*)(Vd) + cA*16);     \
    gld_lds16(Vb + rowB*TT + (s1) + gB*8, (char*)(Vd) + cB*16);     \
  } while (0)

#define TILE_BODY(K_, V_, i) do {                                           \
    const bool g0a = ((i) <= jA);                                           \
    float4v sc[2][4];                                                       \
    __builtin_amdgcn_s_setprio(1);                                          \
    _Pragma("unroll")                                                       \
    for (int st = 0; st < 4; ++st) {                                        \
      f16x8 ak0 = *(const f16x8*)((const char*)(K_) + kof0[st]);            \
      f16x8 ak1 = *(const f16x8*)((const char*)(K_) + kof1[st]);            \
      if (g0a) {                                                            \
        float4v s = {};                                                     \
        s = mfma32h(ak0, bq[0][0], s);                                      \
        s = mfma32h(ak1, bq[0][1], s);                                      \
        sc[0][st] = s;                                                      \
      }                                                                     \
      float4v s = {};                                                       \
      s = mfma32h(ak0, bq[1][0], s);                                        \
      s = mfma32h(ak1, bq[1][1], s);                                        \
      sc[1][st] = s;                                                        \
    }                                                                       \
    __builtin_amdgcn_s_setprio(0);                                          \
    if ((i) == jA) {                                                        \
      _Pragma("unroll")                                                     \
      for (int st = 0; st < 4; ++st)                                        \
        _Pragma("unroll")                                                   \
        for (int r = 0; r < 4; ++r)                                         \
          if (st*16 + quad*4 + r > ql) sc[0][st][r] = -1e30f;               \
    }                                                                       \
    if ((i) == nt - 1) {                                                    \
      _Pragma("unroll")                                                     \
      for (int st = 0; st < 4; ++st)                                        \
        _Pragma("unroll")                                                   \
        for (int r = 0; r < 4; ++r)                                         \
          if (st*16 + quad*4 + r > ql) sc[1][st][r] = -1e30f;               \
    }                                                                       \
    f16x8 ap8[2][2];                                                        \
    _Pragma("unroll")                                                       \
    for (int g = 0; g < 2; ++g) {                                           \
      if (g == 0 && !g0a) continue;                                         \
      _Pragma("unroll")                                                     \
      for (int sp = 0; sp < 2; ++sp) {                                      \
        float p0 = EXP2(sc[g][2*sp][0]);                                    \
        float p1 = EXP2(sc[g][2*sp][1]);                                    \
        float p2 = EXP2(sc[g][2*sp][2]);                                    \
        float p3 = EXP2(sc[g][2*sp][3]);                                    \
        float p4 = EXP2(sc[g][2*sp+1][0]);                                  \
        float p5 = EXP2(sc[g][2*sp+1][1]);                                  \
        float p6 = EXP2(sc[g][2*sp+1][2]);                                  \
        float p7 = EXP2(sc[g][2*sp+1][3]);                                  \
        f16x2 a01 = __builtin_bit_cast(f16x2, __builtin_amdgcn_cvt_pkrtz(p0, p1)); \
        f16x2 a23 = __builtin_bit_cast(f16x2, __builtin_amdgcn_cvt_pkrtz(p2, p3)); \
        f16x2 a45 = __builtin_bit_cast(f16x2, __builtin_amdgcn_cvt_pkrtz(p4, p5)); \
        f16x2 a67 = __builtin_bit_cast(f16x2, __builtin_amdgcn_cvt_pkrtz(p6, p7)); \
        f16x4 alo = __builtin_shufflevector(a01, a23, 0, 1, 2, 3);          \
        f16x4 ahi = __builtin_shufflevector(a45, a67, 0, 1, 2, 3);          \
        ap8[g][sp] = __builtin_shufflevector(alo, ahi, 0,1,2,3,4,5,6,7);    \
      }                                                                     \
      ol[g] = mfma32h(ap8[g][0], ones8, ol[g]);                             \
      ol[g] = mfma32h(ap8[g][1], ones8, ol[g]);                             \
    }                                                                       \
    __builtin_amdgcn_s_setprio(1);                                          \
    _Pragma("unroll")                                                       \
    for (int sp = 0; sp < 2; ++sp)                                          \
      _Pragma("unroll")                                                     \
      for (int dt = 0; dt < 4; ++dt) {                                      \
        f16x4 bl = *(const f16x4*)((const char*)(V_) + vof[2*sp][dt]);      \
        f16x4 bh2 = *(const f16x4*)((const char*)(V_) + vof[2*sp+1][dt]);   \
        f16x8 bv8 = __builtin_shufflevector(bl, bh2, 0,1,2,3,4,5,6,7);      \
        if (g0a) o[0][dt] = mfma32h(ap8[0][sp], bv8, o[0][dt]);             \
        o[1][dt] = mfma32h(ap8[1][sp], bv8, o[1][dt]);                      \
      }                                                                     \
    __builtin_amdgcn_s_setprio(0);                                          \
  } while (0)

  // prologue: tile 0 -> buf 0
  PREFETCH(0, Ks0, Vt0);

  for (int ii = 0; ii < nt; ii += 2) {
    __syncthreads();                       // buf0 (tile ii) resident
    if (ii + 1 < nt) PREFETCH((ii+1)*64, Ks1, Vt1);
    TILE_BODY(Ks0, Vt0, ii);
    if (ii + 1 < nt) {
      __syncthreads();                     // buf1 (tile ii+1) resident
      if (ii + 2 < nt) PREFETCH((ii+2)*64, Ks0, Vt0);
      TILE_BODY(Ks1, Vt1, ii+1);
    }
  }
#undef TILE_BODY
#undef PREFETCH

  // epilogue: normalize; denom already in row layout
#pragma unroll
  for (int g = 0; g < 2; ++g) {
    int qg = g ? qg1 : qg0;
#pragma unroll
    for (int r = 0; r < 4; ++r) {
      float inv_r = 1.0f / ol[g][r];
      int t = qg + wv*16 + quad*4 + r;
#pragma unroll
      for (int dt = 0; dt < 4; ++dt)
        ab[(b*TT + t)*DIMN + h*HD + dt*16 + l16] = f2bf(o[g][dt][r] * inv_r);
    }
  }
}

// ---------------- output GEMM: ab[8192,1024] @ woutT -> fp32 out ----------------
__global__ __launch_bounds__(256) void k_gemm_out(
    const u16* __restrict__ ab, const u16* __restrict__ wT, float* __restrict__ out)
{
  __shared__ __align__(16) u16 As[128*32];
  __shared__ __align__(16) u16 Bs[128*32];
  const int m0 = blockIdx.x * 128, n0 = blockIdx.y * 128;
  const int tid = threadIdx.x;
  const int lane = tid & 63, wv = tid >> 6;
  const int quad = lane >> 4, l16 = lane & 15;
  const int wm = (wv >> 1) * 64, wn = (wv & 1) * 64;
  const int c0 = tid, c1 = tid + 256;
  const u16* ga0 = ab + (m0 + (c0 >> 2)) * DIMN + (c0 & 3) * 8;
  const u16* ga1 = ab + (m0 + (c1 >> 2)) * DIMN + (c1 & 3) * 8;
  const u16* gb0 = wT + (n0 + (c0 >> 2)) * DIMN + (c0 & 3) * 8;
  const u16* gb1 = wT + (n0 + (c1 >> 2)) * DIMN + (c1 & 3) * 8;
  char* la0 = (char*)As + c0 * 16; char* la1 = (char*)As + c1 * 16;
  char* lb0 = (char*)Bs + c0 * 16; char* lb1 = (char*)Bs + c1 * 16;

  float4v acc[4][4] = {};

  for (int kt = 0; kt < DIMN; kt += 32) {
    gld_lds16(ga0 + kt, la0);
    gld_lds16(ga1 + kt, la1);
    gld_lds16(gb0 + kt, lb0);
    gld_lds16(gb1 + kt, lb1);
    __syncthreads();
    bf16x8 af[4], bfv[4];
#pragma unroll
    for (int mt = 0; mt < 4; ++mt)
      af[mt] = *(const bf16x8*)&As[(wm + mt*16 + l16)*32 + quad*8];
#pragma unroll
    for (int nt = 0; nt < 4; ++nt)
      bfv[nt] = *(const bf16x8*)&Bs[(wn + nt*16 + l16)*32 + quad*8];
#pragma unroll
    for (int mt = 0; mt < 4; ++mt)
#pragma unroll
      for (int nt = 0; nt < 4; ++nt)
        acc[mt][nt] = mfma16bf(af[mt], bfv[nt], acc[mt][nt]);
    __syncthreads();
  }
#pragma unroll
  for (int mt = 0; mt < 4; ++mt)
#pragma unroll
    for (int nt = 0; nt < 4; ++nt) {
      int col = n0 + wn + nt*16 + l16;
#pragma unroll
      for (int r = 0; r < 4; ++r) {
        int row = m0 + wm + mt*16 + quad*4 + r;
        out[row*DIMN + col] = acc[mt][nt][r];
      }
    }
}

extern "C" void kernel_launch(void* const* d_in, const int* in_sizes, int n_in,
                              void* d_out, int out_size, void* d_ws, size_t ws_size,
                              hipStream_t stream) {
  const float* x     = (const float*)d_in[0];
  const float* w_qkv = (const float*)d_in[1];
  const float* w_out = (const float*)d_in[2];
  float* out = (float*)d_out;
  char* ws = (char*)d_ws;
  u16* xb    = (u16*)(ws);
  u16* wqkvT = (u16*)(ws + (16u << 20));
  u16* woutT = (u16*)(ws + (22u << 20));
  u16* qbuf  = (u16*)(ws + (24u << 20));
  u16* kbuf  = (u16*)(ws + (40u << 20));
  u16* vbuf  = (u16*)(ws + (56u << 20));
  u16* abuf  = xb;  // x dead after QKV GEMM; reuse for attention output

  k_prep<<<dim3(PREP_CVT + PREP_TQKV + PREP_TOUT), 256, 0, stream>>>(
      x, xb, w_qkv, wqkvT, w_out, woutT);
  k_gemm_qkv<<<dim3(MTOK/128, N3/128), 256, 0, stream>>>(xb, wqkvT, qbuf, kbuf, vbuf);
  k_attn<<<dim3(16 * BB * NH), 256, 0, stream>>>(qbuf, kbuf, vbuf, abuf);
  k_gemm_out<<<dim3(MTOK/128, DIMN/128), 256, 0, stream>>>(abuf, woutT, out);
}